// Round 6
// baseline (932.801 us; speedup 1.0000x reference)
//
#include <hip/hip_runtime.h>
#include <math.h>

// AttentionBlock: B=8, C=256, HW=4096. Round 6:
//   attn: XCD-aware grid (b = bid&7 -> per-XCD L2-resident KV), KV tile 32,
//         LDS 32KB -> 4 blocks/CU (4 waves/SIMD), defer-rescale (THR=8).
//   K1/K2/K4 unchanged from round 5.
// ws: s,t (16KB) | Qt 16MB | Kt 16MB | V 16MB | tmp fp32 32MB

#define Bn 8
#define Cn 256
#define HWn 4096
#define Gn 8
#define CPGn 32
#define Mqkv 768
#define EPSf 1e-5f
#define QSCALEf 0.0625f   // 1/sqrt(256), exact in bf16
#define RTHR 8.0f

typedef short bf16x8 __attribute__((ext_vector_type(8)));
typedef float f32x4 __attribute__((ext_vector_type(4)));

__device__ __forceinline__ unsigned short f2bf(float f) {
  union { float f; unsigned u; } v; v.f = f;
  unsigned r = v.u + 0x7FFFu + ((v.u >> 16) & 1u);  // RNE
  return (unsigned short)(r >> 16);
}

__device__ __forceinline__ int cvt_pk_bf16(float lo, float hi) {
  int d;
  asm("v_cvt_pk_bf16_f32 %0, %1, %2" : "=v"(d) : "v"(lo), "v"(hi));
  return d;
}

// ---------------- K1: group-norm stats -> per-channel affine ----------------
__global__ __launch_bounds__(1024)
void gn_stats_kernel(const float* __restrict__ x, const float* __restrict__ gn_w,
                     const float* __restrict__ gn_b, float* __restrict__ s_out,
                     float* __restrict__ t_out) {
  const int b = blockIdx.x / Gn, g = blockIdx.x % Gn;
  const float4* base = (const float4*)(x + ((size_t)(b * Cn + g * CPGn)) * HWn);
  const int n4 = CPGn * HWn / 4;
  float sum = 0.f, sq = 0.f;
  for (int i = threadIdx.x; i < n4; i += 1024) {
    float4 v = base[i];
    sum += (v.x + v.y) + (v.z + v.w);
    sq  += (v.x * v.x + v.y * v.y) + (v.z * v.z + v.w * v.w);
  }
  __shared__ float ss[1024], s2[1024];
  ss[threadIdx.x] = sum; s2[threadIdx.x] = sq;
  __syncthreads();
  for (int off = 512; off > 0; off >>= 1) {
    if ((int)threadIdx.x < off) {
      ss[threadIdx.x] += ss[threadIdx.x + off];
      s2[threadIdx.x] += s2[threadIdx.x + off];
    }
    __syncthreads();
  }
  if (threadIdx.x < CPGn) {
    const float inv_n = 1.f / (float)(CPGn * HWn);
    float mean = ss[0] * inv_n;
    float var  = s2[0] * inv_n - mean * mean;
    float rstd = rsqrtf(var + EPSf);
    int c = g * CPGn + (int)threadIdx.x;
    float sc = gn_w[c] * rstd;
    s_out[b * Cn + c] = sc;
    t_out[b * Cn + c] = gn_b[c] - mean * sc;
  }
}

// ---------------- K2: QKV GEMM (fp32) -> bf16 Q^T/K^T/V ----------------
__global__ __launch_bounds__(256)
void qkv_gemm_kernel(const float* __restrict__ x, const float* __restrict__ w,
                     const float* __restrict__ wb, const float* __restrict__ s_aff,
                     const float* __restrict__ t_aff, unsigned short* __restrict__ Qt,
                     unsigned short* __restrict__ Kt, unsigned short* __restrict__ Vb) {
  const int b = blockIdx.z;
  const int m0 = blockIdx.y * 64, n0 = blockIdx.x * 64;
  const int tid = threadIdx.x, tx = tid & 15, ty = tid >> 4;
  __shared__ float As[16][68];
  __shared__ float Bs[16][68];
  const float* xb = x + (size_t)b * Cn * HWn;
  const float* sb = s_aff + b * Cn;
  const float* tb = t_aff + b * Cn;
  float acc[4][4] = {};
  const int am = tid >> 2, ak = (tid & 3) * 4;
  const int bk = tid >> 4, bn = (tid & 15) * 4;
  for (int k0 = 0; k0 < Cn; k0 += 16) {
    {
      float4 a = *(const float4*)(w + (size_t)(m0 + am) * Cn + (k0 + ak));
      As[ak + 0][am] = a.x; As[ak + 1][am] = a.y; As[ak + 2][am] = a.z; As[ak + 3][am] = a.w;
      int c = k0 + bk;
      float4 v = *(const float4*)(xb + (size_t)c * HWn + (n0 + bn));
      float sc = sb[c], sh = tb[c];
      Bs[bk][bn + 0] = v.x * sc + sh; Bs[bk][bn + 1] = v.y * sc + sh;
      Bs[bk][bn + 2] = v.z * sc + sh; Bs[bk][bn + 3] = v.w * sc + sh;
    }
    __syncthreads();
#pragma unroll
    for (int kk = 0; kk < 16; ++kk) {
      float4 av = *(const float4*)&As[kk][ty * 4];
      float4 bv = *(const float4*)&Bs[kk][tx * 4];
      float aa[4] = {av.x, av.y, av.z, av.w};
      float bb[4] = {bv.x, bv.y, bv.z, bv.w};
#pragma unroll
      for (int i2 = 0; i2 < 4; ++i2)
#pragma unroll
        for (int j2 = 0; j2 < 4; ++j2)
          acc[i2][j2] = fmaf(aa[i2], bb[j2], acc[i2][j2]);
    }
    __syncthreads();
  }
  float bias[4];
#pragma unroll
  for (int i2 = 0; i2 < 4; ++i2) bias[i2] = wb[m0 + ty * 4 + i2];

  if (m0 < 512) {  // Q or K -> transposed [n][c] bf16; Q prescaled by 1/16
    unsigned short* dst = (m0 < 256) ? Qt : Kt;
    const float scl = (m0 < 256) ? QSCALEf : 1.0f;
    const int cbase = (m0 & 255) + ty * 4;
#pragma unroll
    for (int j2 = 0; j2 < 4; ++j2) {
      int n = n0 + tx * 4 + j2;
      ushort4 pk;
      pk.x = f2bf((acc[0][j2] + bias[0]) * scl);
      pk.y = f2bf((acc[1][j2] + bias[1]) * scl);
      pk.z = f2bf((acc[2][j2] + bias[2]) * scl);
      pk.w = f2bf((acc[3][j2] + bias[3]) * scl);
      *(ushort4*)(dst + ((size_t)(b * HWn + n) * Cn + cbase)) = pk;
    }
  } else {  // V -> [c][n] bf16
#pragma unroll
    for (int i2 = 0; i2 < 4; ++i2) {
      int c = (m0 - 512) + ty * 4 + i2;
      ushort4 pk;
      pk.x = f2bf(acc[i2][0] + bias[i2]);
      pk.y = f2bf(acc[i2][1] + bias[i2]);
      pk.z = f2bf(acc[i2][2] + bias[i2]);
      pk.w = f2bf(acc[i2][3] + bias[i2]);
      *(ushort4*)(Vb + ((size_t)(b * Cn + c) * HWn + n0 + tx * 4)) = pk;
    }
  }
}

// ---------------- K3: flash attention, bf16 MFMA ----------------
// 1D grid of 512: b = bid&7 (XCD-resident KV), qtile i0 = (bid>>3)*64.
// 4 waves x 16 q-rows. KV tile = 32 j. LDS 32KB chunk-linear (16B chunks):
//   Ks chunk = kc*128 + s*64 + lane : K[j=s*16+(lane&15)][c=kc*32+(lane>>4)*8 ..+7]
//   Vs chunk = cs*64 + lane         : V[c=cs*16+(lane&15)][j=(lane>>4)*8 ..+7]
// All LDS reads/writes = lane*16 + imm (conflict-free); perm folded into global addrs.
__global__ __launch_bounds__(256, 4)
void attn_kernel(const unsigned short* __restrict__ Qt,
                 const unsigned short* __restrict__ Kt,
                 const unsigned short* __restrict__ Vb,
                 float* __restrict__ outp) {
  const int bid = blockIdx.x;
  const int b = bid & 7, i0 = (bid >> 3) * 64;
  const int tid = threadIdx.x;
  const int wv = tid >> 6, l = tid & 63;
  const int l15 = l & 15, lq = l >> 4;

  __shared__ unsigned short Ks[8192];  // 16KB
  __shared__ unsigned short Vs[8192];  // 16KB
  char* KsB = (char*)Ks;
  char* VsB = (char*)Vs;

  const unsigned short* Qb = Qt + ((size_t)b * HWn + i0) * Cn;
  const unsigned short* Kb = Kt + (size_t)b * HWn * Cn;
  const unsigned short* Vg = Vb + (size_t)b * Cn * HWn;

  // hoisted Q fragments (prescaled): B-frag Q[i=l15][k=kc*32+lq*8+t]
  bf16x8 qf[8];
  {
    const unsigned short* qrow = Qb + (size_t)(wv * 16 + l15) * Cn + lq * 8;
#pragma unroll
    for (int kc = 0; kc < 8; ++kc) qf[kc] = *(const bf16x8*)(qrow + kc * 32);
  }

  // staging maps (thread tid owns chunks q*256+tid, q=0..3)
  const int jk = ((tid >> 6) & 1) * 16 + (tid & 15);          // K row j (0..31)
  const int ck = (tid >> 7) * 32 + ((tid >> 4) & 3) * 8;      // K col base; +q*64
  const int cv = (tid >> 6) * 16 + (tid & 15);                // V row c base; +q*64
  const int jv = ((tid >> 4) & 3) * 8;                        // V col j
  const unsigned short* gK = Kb + (size_t)jk * Cn + ck;
  const unsigned short* gV = Vg + (size_t)cv * HWn + jv;

  // P redistribution lanes (select post-shuffle by shi = lq>>1)
  const int laneA = l15 + ((lq & 1) << 5);
  const int laneB = laneA + 16;
  const int shi = lq >> 1;

  bf16x8 kst[4], vst[4];
#pragma unroll
  for (int q = 0; q < 4; ++q) kst[q] = *(const bf16x8*)(gK + q * 64);
#pragma unroll
  for (int q = 0; q < 4; ++q) vst[q] = *(const bf16x8*)(gV + (size_t)q * 64 * HWn);
  gK += 32 * Cn; gV += 32;

  f32x4 o_acc[16];
#pragma unroll
  for (int cs = 0; cs < 16; ++cs) o_acc[cs] = (f32x4)(0.f);
  float m_i = -INFINITY, l_i = 0.f;

#pragma unroll 1
  for (int t = 0; t < 128; ++t) {
    // ---- write staged tile to LDS ----
#pragma unroll
    for (int q = 0; q < 4; ++q) *(bf16x8*)(KsB + tid * 16 + q * 4096) = kst[q];
#pragma unroll
    for (int q = 0; q < 4; ++q) *(bf16x8*)(VsB + tid * 16 + q * 4096) = vst[q];
    __syncthreads();
    // ---- issue next-tile loads (overlap with compute) ----
    if (t < 127) {
#pragma unroll
      for (int q = 0; q < 4; ++q) kst[q] = *(const bf16x8*)(gK + q * 64);
#pragma unroll
      for (int q = 0; q < 4; ++q) vst[q] = *(const bf16x8*)(gV + (size_t)q * 64 * HWn);
      gK += 32 * Cn; gV += 32;
    }

    // ---- S^T = K Q^T: lane holds S[i=l15][j=16s+4lq+r], s=0..1 ----
    f32x4 s0 = (f32x4)(0.f), s1 = (f32x4)(0.f);
#pragma unroll
    for (int kc = 0; kc < 8; ++kc) {
      bf16x8 kf0 = *(const bf16x8*)(KsB + l * 16 + kc * 2048);
      bf16x8 kf1 = *(const bf16x8*)(KsB + l * 16 + kc * 2048 + 1024);
      s0 = __builtin_amdgcn_mfma_f32_16x16x32_bf16(kf0, qf[kc], s0, 0, 0, 0);
      s1 = __builtin_amdgcn_mfma_f32_16x16x32_bf16(kf1, qf[kc], s1, 0, 0, 0);
    }

    // ---- per-lane online softmax (defer-rescale, THR=8) ----
    float p[2][4];
#pragma unroll
    for (int r = 0; r < 4; ++r) { p[0][r] = s0[r]; p[1][r] = s1[r]; }
    float rm = fmaxf(fmaxf(fmaxf(p[0][0], p[0][1]), fmaxf(p[0][2], p[0][3])),
                     fmaxf(fmaxf(p[1][0], p[1][1]), fmaxf(p[1][2], p[1][3])));
    rm = fmaxf(rm, __shfl_xor(rm, 16));
    rm = fmaxf(rm, __shfl_xor(rm, 32));
    if (!__all(rm - m_i <= RTHR)) {
      float mn = fmaxf(m_i, rm);
      float alpha = __expf(m_i - mn);
      m_i = mn;
      l_i *= alpha;
      float a0 = __shfl(alpha, 4 * lq + 0);
      float a1 = __shfl(alpha, 4 * lq + 1);
      float a2 = __shfl(alpha, 4 * lq + 2);
      float a3 = __shfl(alpha, 4 * lq + 3);
#pragma unroll
      for (int cs = 0; cs < 16; ++cs) {
        o_acc[cs][0] *= a0; o_acc[cs][1] *= a1;
        o_acc[cs][2] *= a2; o_acc[cs][3] *= a3;
      }
    }
    float rs = 0.f;
#pragma unroll
    for (int s = 0; s < 2; ++s)
#pragma unroll
      for (int r = 0; r < 4; ++r) { float e = __expf(p[s][r] - m_i); p[s][r] = e; rs += e; }
    rs += __shfl_xor(rs, 16);
    rs += __shfl_xor(rs, 32);
    l_i += rs;

    // ---- pack P: d[s][u] = bf16 pair P[i][s*16+4lq+2u, +1] ----
    int d00 = cvt_pk_bf16(p[0][0], p[0][1]), d01 = cvt_pk_bf16(p[0][2], p[0][3]);
    int d10 = cvt_pk_bf16(p[1][0], p[1][1]), d11 = cvt_pk_bf16(p[1][2], p[1][3]);
    // ---- redistribute to PV A-frag pa = P[i=l15][j=lq*8+t] ----
    int A00 = __shfl(d00, laneA), A01 = __shfl(d01, laneA);
    int A10 = __shfl(d10, laneA), A11 = __shfl(d11, laneA);
    int B00 = __shfl(d00, laneB), B01 = __shfl(d01, laneB);
    int B10 = __shfl(d10, laneB), B11 = __shfl(d11, laneB);
    union { int w[4]; bf16x8 v; } pa;
    pa.w[0] = shi ? A10 : A00; pa.w[1] = shi ? A11 : A01;
    pa.w[2] = shi ? B10 : B00; pa.w[3] = shi ? B11 : B01;

    // ---- O += P V ----
#pragma unroll
    for (int cs = 0; cs < 16; ++cs) {
      bf16x8 vf = *(const bf16x8*)(VsB + l * 16 + cs * 1024);
      o_acc[cs] = __builtin_amdgcn_mfma_f32_16x16x32_bf16(pa.v, vf, o_acc[cs], 0, 0, 0);
    }
    __syncthreads();
  }

  // ---- epilogue: O /= l, write tmp fp32 [c][i] ----
  float il = 1.f / l_i;
  float i0v = __shfl(il, 4 * lq + 0);
  float i1v = __shfl(il, 4 * lq + 1);
  float i2v = __shfl(il, 4 * lq + 2);
  float i3v = __shfl(il, 4 * lq + 3);
  float* ob = outp + (size_t)b * Cn * HWn;
  const int ibase = i0 + wv * 16 + lq * 4;
#pragma unroll
  for (int cs = 0; cs < 16; ++cs) {
    int c = cs * 16 + l15;
    float4 r4;
    r4.x = o_acc[cs][0] * i0v;
    r4.y = o_acc[cs][1] * i1v;
    r4.z = o_acc[cs][2] * i2v;
    r4.w = o_acc[cs][3] * i3v;
    *(float4*)(ob + (size_t)c * HWn + ibase) = r4;
  }
}

// ---------------- K4: output projection + bias + residual ----------------
__global__ __launch_bounds__(256)
void out_gemm_kernel(const float* __restrict__ tmp, const float* __restrict__ w,
                     const float* __restrict__ wb, const float* __restrict__ xres,
                     float* __restrict__ y) {
  const int b = blockIdx.z;
  const int m0 = blockIdx.y * 64, n0 = blockIdx.x * 64;
  const int tid = threadIdx.x, tx = tid & 15, ty = tid >> 4;
  __shared__ float As[16][68];
  __shared__ float Bs[16][68];
  const float* tb = tmp + (size_t)b * Cn * HWn;
  float acc[4][4] = {};
  const int am = tid >> 2, ak = (tid & 3) * 4;
  const int bk = tid >> 4, bn = (tid & 15) * 4;
  for (int k0 = 0; k0 < Cn; k0 += 16) {
    {
      float4 a = *(const float4*)(w + (size_t)(m0 + am) * Cn + (k0 + ak));
      As[ak + 0][am] = a.x; As[ak + 1][am] = a.y; As[ak + 2][am] = a.z; As[ak + 3][am] = a.w;
      int c = k0 + bk;
      float4 vv = *(const float4*)(tb + (size_t)c * HWn + (n0 + bn));
      Bs[bk][bn + 0] = vv.x; Bs[bk][bn + 1] = vv.y; Bs[bk][bn + 2] = vv.z; Bs[bk][bn + 3] = vv.w;
    }
    __syncthreads();
#pragma unroll
    for (int kk = 0; kk < 16; ++kk) {
      float4 av = *(const float4*)&As[kk][ty * 4];
      float4 bv = *(const float4*)&Bs[kk][tx * 4];
      float aa[4] = {av.x, av.y, av.z, av.w};
      float bb[4] = {bv.x, bv.y, bv.z, bv.w};
#pragma unroll
      for (int i2 = 0; i2 < 4; ++i2)
#pragma unroll
        for (int j2 = 0; j2 < 4; ++j2)
          acc[i2][j2] = fmaf(aa[i2], bb[j2], acc[i2][j2]);
    }
    __syncthreads();
  }
  float* yb = y + (size_t)b * Cn * HWn;
  const float* xb = xres + (size_t)b * Cn * HWn;
#pragma unroll
  for (int i2 = 0; i2 < 4; ++i2) {
    int m = m0 + ty * 4 + i2;
    float bias = wb[m];
    float4 xr = *(const float4*)(xb + (size_t)m * HWn + n0 + tx * 4);
    float4 r;
    r.x = acc[i2][0] + bias + xr.x; r.y = acc[i2][1] + bias + xr.y;
    r.z = acc[i2][2] + bias + xr.z; r.w = acc[i2][3] + bias + xr.w;
    *(float4*)(yb + (size_t)m * HWn + n0 + tx * 4) = r;
  }
}

extern "C" void kernel_launch(void* const* d_in, const int* in_sizes, int n_in,
                              void* d_out, int out_size, void* d_ws, size_t ws_size,
                              hipStream_t stream) {
  (void)in_sizes; (void)n_in; (void)out_size; (void)ws_size;
  const float* x     = (const float*)d_in[0];
  const float* gn_w  = (const float*)d_in[1];
  const float* gn_b  = (const float*)d_in[2];
  const float* qkv_w = (const float*)d_in[3];
  const float* qkv_b = (const float*)d_in[4];
  const float* out_w = (const float*)d_in[5];
  const float* out_b = (const float*)d_in[6];
  float* out = (float*)d_out;

  char* ws = (char*)d_ws;
  float* s_aff = (float*)ws;                                   // B*C
  float* t_aff = s_aff + Bn * Cn;                              // B*C
  unsigned short* Qt = (unsigned short*)(ws + 16384);          // 16MB
  unsigned short* Kt = Qt + (size_t)Bn * HWn * Cn;             // 16MB
  unsigned short* Vb = Kt + (size_t)Bn * HWn * Cn;             // 16MB
  float* tmp = (float*)(Vb + (size_t)Bn * HWn * Cn);           // 32MB

  gn_stats_kernel<<<dim3(Bn * Gn), 1024, 0, stream>>>(x, gn_w, gn_b, s_aff, t_aff);
  qkv_gemm_kernel<<<dim3(64, 12, Bn), 256, 0, stream>>>(x, qkv_w, qkv_b, s_aff, t_aff, Qt, Kt, Vb);
  attn_kernel<<<dim3(512), 256, 0, stream>>>(Qt, Kt, Vb, tmp);
  out_gemm_kernel<<<dim3(64, 4, Bn), 256, 0, stream>>>(tmp, out_w, out_b, x, out);
}

// Round 7
// 502.519 us; speedup vs baseline: 1.8563x; 1.8563x over previous
//
#include <hip/hip_runtime.h>
#include <math.h>

// AttentionBlock: B=8, C=256, HW=4096. Round 7:
//   attn = round-5 proven structure (64-j tile, 64KB LDS, launch_bounds(256,2))
//        + XCD-aware grid (b = bid&7 -> per-XCD L2-resident KV)   [verified R6: FETCH 139->36MB]
//        + defer-rescale THR=8                                     [verified R6: numerics OK]
//   R6's (256,4) bound caused VGPR spills (WRITE_SIZE 1.16GB scratch) -> reverted.
// ws: s,t (16KB) | Qt 16MB | Kt 16MB | V 16MB | tmp fp32 32MB

#define Bn 8
#define Cn 256
#define HWn 4096
#define Gn 8
#define CPGn 32
#define Mqkv 768
#define EPSf 1e-5f
#define QSCALEf 0.0625f   // 1/sqrt(256), exact in bf16
#define RTHR 8.0f

typedef short bf16x8 __attribute__((ext_vector_type(8)));
typedef float f32x4 __attribute__((ext_vector_type(4)));

__device__ __forceinline__ unsigned short f2bf(float f) {
  union { float f; unsigned u; } v; v.f = f;
  unsigned r = v.u + 0x7FFFu + ((v.u >> 16) & 1u);  // RNE
  return (unsigned short)(r >> 16);
}

__device__ __forceinline__ int cvt_pk_bf16(float lo, float hi) {
  int d;
  asm("v_cvt_pk_bf16_f32 %0, %1, %2" : "=v"(d) : "v"(lo), "v"(hi));
  return d;
}

// ---------------- K1: group-norm stats -> per-channel affine ----------------
__global__ __launch_bounds__(1024)
void gn_stats_kernel(const float* __restrict__ x, const float* __restrict__ gn_w,
                     const float* __restrict__ gn_b, float* __restrict__ s_out,
                     float* __restrict__ t_out) {
  const int b = blockIdx.x / Gn, g = blockIdx.x % Gn;
  const float4* base = (const float4*)(x + ((size_t)(b * Cn + g * CPGn)) * HWn);
  const int n4 = CPGn * HWn / 4;
  float sum = 0.f, sq = 0.f;
  for (int i = threadIdx.x; i < n4; i += 1024) {
    float4 v = base[i];
    sum += (v.x + v.y) + (v.z + v.w);
    sq  += (v.x * v.x + v.y * v.y) + (v.z * v.z + v.w * v.w);
  }
  __shared__ float ss[1024], s2[1024];
  ss[threadIdx.x] = sum; s2[threadIdx.x] = sq;
  __syncthreads();
  for (int off = 512; off > 0; off >>= 1) {
    if ((int)threadIdx.x < off) {
      ss[threadIdx.x] += ss[threadIdx.x + off];
      s2[threadIdx.x] += s2[threadIdx.x + off];
    }
    __syncthreads();
  }
  if (threadIdx.x < CPGn) {
    const float inv_n = 1.f / (float)(CPGn * HWn);
    float mean = ss[0] * inv_n;
    float var  = s2[0] * inv_n - mean * mean;
    float rstd = rsqrtf(var + EPSf);
    int c = g * CPGn + (int)threadIdx.x;
    float sc = gn_w[c] * rstd;
    s_out[b * Cn + c] = sc;
    t_out[b * Cn + c] = gn_b[c] - mean * sc;
  }
}

// ---------------- K2: QKV GEMM (fp32) -> bf16 Q^T/K^T/V ----------------
__global__ __launch_bounds__(256)
void qkv_gemm_kernel(const float* __restrict__ x, const float* __restrict__ w,
                     const float* __restrict__ wb, const float* __restrict__ s_aff,
                     const float* __restrict__ t_aff, unsigned short* __restrict__ Qt,
                     unsigned short* __restrict__ Kt, unsigned short* __restrict__ Vb) {
  const int b = blockIdx.z;
  const int m0 = blockIdx.y * 64, n0 = blockIdx.x * 64;
  const int tid = threadIdx.x, tx = tid & 15, ty = tid >> 4;
  __shared__ float As[16][68];
  __shared__ float Bs[16][68];
  const float* xb = x + (size_t)b * Cn * HWn;
  const float* sb = s_aff + b * Cn;
  const float* tb = t_aff + b * Cn;
  float acc[4][4] = {};
  const int am = tid >> 2, ak = (tid & 3) * 4;
  const int bk = tid >> 4, bn = (tid & 15) * 4;
  for (int k0 = 0; k0 < Cn; k0 += 16) {
    {
      float4 a = *(const float4*)(w + (size_t)(m0 + am) * Cn + (k0 + ak));
      As[ak + 0][am] = a.x; As[ak + 1][am] = a.y; As[ak + 2][am] = a.z; As[ak + 3][am] = a.w;
      int c = k0 + bk;
      float4 v = *(const float4*)(xb + (size_t)c * HWn + (n0 + bn));
      float sc = sb[c], sh = tb[c];
      Bs[bk][bn + 0] = v.x * sc + sh; Bs[bk][bn + 1] = v.y * sc + sh;
      Bs[bk][bn + 2] = v.z * sc + sh; Bs[bk][bn + 3] = v.w * sc + sh;
    }
    __syncthreads();
#pragma unroll
    for (int kk = 0; kk < 16; ++kk) {
      float4 av = *(const float4*)&As[kk][ty * 4];
      float4 bv = *(const float4*)&Bs[kk][tx * 4];
      float aa[4] = {av.x, av.y, av.z, av.w};
      float bb[4] = {bv.x, bv.y, bv.z, bv.w};
#pragma unroll
      for (int i2 = 0; i2 < 4; ++i2)
#pragma unroll
        for (int j2 = 0; j2 < 4; ++j2)
          acc[i2][j2] = fmaf(aa[i2], bb[j2], acc[i2][j2]);
    }
    __syncthreads();
  }
  float bias[4];
#pragma unroll
  for (int i2 = 0; i2 < 4; ++i2) bias[i2] = wb[m0 + ty * 4 + i2];

  if (m0 < 512) {  // Q or K -> transposed [n][c] bf16; Q prescaled by 1/16
    unsigned short* dst = (m0 < 256) ? Qt : Kt;
    const float scl = (m0 < 256) ? QSCALEf : 1.0f;
    const int cbase = (m0 & 255) + ty * 4;
#pragma unroll
    for (int j2 = 0; j2 < 4; ++j2) {
      int n = n0 + tx * 4 + j2;
      ushort4 pk;
      pk.x = f2bf((acc[0][j2] + bias[0]) * scl);
      pk.y = f2bf((acc[1][j2] + bias[1]) * scl);
      pk.z = f2bf((acc[2][j2] + bias[2]) * scl);
      pk.w = f2bf((acc[3][j2] + bias[3]) * scl);
      *(ushort4*)(dst + ((size_t)(b * HWn + n) * Cn + cbase)) = pk;
    }
  } else {  // V -> [c][n] bf16
#pragma unroll
    for (int i2 = 0; i2 < 4; ++i2) {
      int c = (m0 - 512) + ty * 4 + i2;
      ushort4 pk;
      pk.x = f2bf(acc[i2][0] + bias[i2]);
      pk.y = f2bf(acc[i2][1] + bias[i2]);
      pk.z = f2bf(acc[i2][2] + bias[i2]);
      pk.w = f2bf(acc[i2][3] + bias[i2]);
      *(ushort4*)(Vb + ((size_t)(b * Cn + c) * HWn + n0 + tx * 4)) = pk;
    }
  }
}

// ---------------- K3: flash attention, bf16 MFMA, in-register softmax ----------------
// 1D grid 512: b = bid&7 (XCD-resident KV), i0 = (bid>>3)*64. 4 waves x 16 q-rows.
// LDS chunk-linear (16B chunks):
//   Ks chunk = kc*256 + s*64 + lane : K[j=s*16+(lane&15)][c=kc*32+(lane>>4)*8 ..+7]
//   Vs chunk = jc*1024 + cs*64 + lane: V[c=cs*16+(lane&15)][j=jc*32+(lane>>4)*8 ..+7]
// All LDS ops = lane*16 + imm (conflict-free); perm folded into global staging addrs.
__global__ __launch_bounds__(256, 2)
void attn_kernel(const unsigned short* __restrict__ Qt,
                 const unsigned short* __restrict__ Kt,
                 const unsigned short* __restrict__ Vb,
                 float* __restrict__ outp) {
  const int bid = blockIdx.x;
  const int b = bid & 7, i0 = (bid >> 3) * 64;
  const int tid = threadIdx.x;
  const int wv = tid >> 6, l = tid & 63;
  const int l15 = l & 15, lq = l >> 4;

  __shared__ unsigned short Ks[16384];  // 32KB
  __shared__ unsigned short Vs[16384];  // 32KB
  char* KsB = (char*)Ks;
  char* VsB = (char*)Vs;

  const unsigned short* Qb = Qt + ((size_t)b * HWn + i0) * Cn;
  const unsigned short* Kb = Kt + (size_t)b * HWn * Cn;
  const unsigned short* Vg = Vb + (size_t)b * Cn * HWn;

  // hoisted Q fragments (prescaled by 1/16): B-frag Q[i=l15][k=kc*32+lq*8+t]
  bf16x8 qf[8];
  {
    const unsigned short* qrow = Qb + (size_t)(wv * 16 + l15) * Cn + lq * 8;
#pragma unroll
    for (int kc = 0; kc < 8; ++kc) qf[kc] = *(const bf16x8*)(qrow + kc * 32);
  }

  // staging: thread tid owns LDS chunks q*256+tid (q=0..7)
  const int jt  = ((tid >> 6) << 4) | (tid & 15);
  const int lqt = (tid >> 4) & 3;
  const unsigned short* gK = Kb + (size_t)jt * Cn + lqt * 8;   // +q*32 elems
  const unsigned short* gV = Vg + (size_t)jt * HWn + lqt * 8;  // +(q&3)*64*HWn + (q>>2)*32

  // P redistribution lanes (select post-shuffle by shi = lq>>1)
  const int laneA = l15 + ((lq & 1) << 5);
  const int laneB = laneA + 16;
  const int shi = lq >> 1;

  bf16x8 kst[8], vst[8];
#pragma unroll
  for (int q = 0; q < 8; ++q) kst[q] = *(const bf16x8*)(gK + q * 32);
#pragma unroll
  for (int q = 0; q < 8; ++q)
    vst[q] = *(const bf16x8*)(gV + (size_t)(q & 3) * 64 * HWn + (q >> 2) * 32);
  gK += 64 * Cn; gV += 64;

  f32x4 o_acc[16];
#pragma unroll
  for (int cs = 0; cs < 16; ++cs) o_acc[cs] = (f32x4)(0.f);
  float m_i = -INFINITY, l_i = 0.f;

#pragma unroll 1
  for (int t = 0; t < 64; ++t) {
    // ---- write staged tile to LDS (compiler inserts vmcnt wait) ----
#pragma unroll
    for (int q = 0; q < 8; ++q) *(bf16x8*)(KsB + tid * 16 + q * 4096) = kst[q];
#pragma unroll
    for (int q = 0; q < 8; ++q) *(bf16x8*)(VsB + tid * 16 + q * 4096) = vst[q];
    __syncthreads();
    // ---- issue next-tile loads (overlap with compute) ----
    if (t < 63) {
#pragma unroll
      for (int q = 0; q < 8; ++q) kst[q] = *(const bf16x8*)(gK + q * 32);
#pragma unroll
      for (int q = 0; q < 8; ++q)
        vst[q] = *(const bf16x8*)(gV + (size_t)(q & 3) * 64 * HWn + (q >> 2) * 32);
      gK += 64 * Cn; gV += 64;
    }

    // ---- S^T = K Q^T: lane holds S[i=l15][j=16s+4lq+r] ----
    f32x4 s_acc[4];
#pragma unroll
    for (int s = 0; s < 4; ++s) s_acc[s] = (f32x4)(0.f);
#pragma unroll
    for (int kc = 0; kc < 8; ++kc) {
#pragma unroll
      for (int s = 0; s < 4; ++s) {
        bf16x8 kf = *(const bf16x8*)(KsB + l * 16 + s * 1024 + kc * 4096);
        s_acc[s] = __builtin_amdgcn_mfma_f32_16x16x32_bf16(kf, qf[kc], s_acc[s], 0, 0, 0);
      }
    }

    // ---- per-lane online softmax, defer-rescale THR=8 ----
    float p[4][4];
    float rm = -INFINITY;
#pragma unroll
    for (int s = 0; s < 4; ++s)
#pragma unroll
      for (int r = 0; r < 4; ++r) { p[s][r] = s_acc[s][r]; rm = fmaxf(rm, p[s][r]); }
    rm = fmaxf(rm, __shfl_xor(rm, 16));
    rm = fmaxf(rm, __shfl_xor(rm, 32));
    if (!__all(rm - m_i <= RTHR)) {
      float mn = fmaxf(m_i, rm);
      float alpha = __expf(m_i - mn);
      m_i = mn;
      l_i *= alpha;
      float a0 = __shfl(alpha, 4 * lq + 0);
      float a1 = __shfl(alpha, 4 * lq + 1);
      float a2 = __shfl(alpha, 4 * lq + 2);
      float a3 = __shfl(alpha, 4 * lq + 3);
#pragma unroll
      for (int cs = 0; cs < 16; ++cs) {
        o_acc[cs][0] *= a0; o_acc[cs][1] *= a1;
        o_acc[cs][2] *= a2; o_acc[cs][3] *= a3;
      }
    }
    float rs = 0.f;
#pragma unroll
    for (int s = 0; s < 4; ++s)
#pragma unroll
      for (int r = 0; r < 4; ++r) { float e = __expf(p[s][r] - m_i); p[s][r] = e; rs += e; }
    rs += __shfl_xor(rs, 16);
    rs += __shfl_xor(rs, 32);
    l_i += rs;

    // ---- pack P to bf16 dwords: d[s][u] = P[i][s*16+4*lq+2u .. +1] ----
    int d00 = cvt_pk_bf16(p[0][0], p[0][1]), d01 = cvt_pk_bf16(p[0][2], p[0][3]);
    int d10 = cvt_pk_bf16(p[1][0], p[1][1]), d11 = cvt_pk_bf16(p[1][2], p[1][3]);
    int d20 = cvt_pk_bf16(p[2][0], p[2][1]), d21 = cvt_pk_bf16(p[2][2], p[2][3]);
    int d30 = cvt_pk_bf16(p[3][0], p[3][1]), d31 = cvt_pk_bf16(p[3][2], p[3][3]);
    // ---- redistribute to PV A-frag pa[jc] = P[i=l15][j=32jc+8lq+t] ----
    int A00 = __shfl(d00, laneA), A01 = __shfl(d01, laneA);
    int A10 = __shfl(d10, laneA), A11 = __shfl(d11, laneA);
    int B00 = __shfl(d00, laneB), B01 = __shfl(d01, laneB);
    int B10 = __shfl(d10, laneB), B11 = __shfl(d11, laneB);
    int A20 = __shfl(d20, laneA), A21 = __shfl(d21, laneA);
    int A30 = __shfl(d30, laneA), A31 = __shfl(d31, laneA);
    int B20 = __shfl(d20, laneB), B21 = __shfl(d21, laneB);
    int B30 = __shfl(d30, laneB), B31 = __shfl(d31, laneB);
    union { int w[4]; bf16x8 v; } pa0, pa1;
    pa0.w[0] = shi ? A10 : A00; pa0.w[1] = shi ? A11 : A01;
    pa0.w[2] = shi ? B10 : B00; pa0.w[3] = shi ? B11 : B01;
    pa1.w[0] = shi ? A30 : A20; pa1.w[1] = shi ? A31 : A21;
    pa1.w[2] = shi ? B30 : B20; pa1.w[3] = shi ? B31 : B21;

    // ---- O += P V ----
#pragma unroll
    for (int cs = 0; cs < 16; ++cs) {
      bf16x8 vf0 = *(const bf16x8*)(VsB + l * 16 + cs * 1024);
      bf16x8 vf1 = *(const bf16x8*)(VsB + l * 16 + cs * 1024 + 16384);
      o_acc[cs] = __builtin_amdgcn_mfma_f32_16x16x32_bf16(pa0.v, vf0, o_acc[cs], 0, 0, 0);
      o_acc[cs] = __builtin_amdgcn_mfma_f32_16x16x32_bf16(pa1.v, vf1, o_acc[cs], 0, 0, 0);
    }
    __syncthreads();
  }

  // ---- epilogue: O /= l, write tmp fp32 [c][i] ----
  float il = 1.f / l_i;
  float i0v = __shfl(il, 4 * lq + 0);
  float i1v = __shfl(il, 4 * lq + 1);
  float i2v = __shfl(il, 4 * lq + 2);
  float i3v = __shfl(il, 4 * lq + 3);
  float* ob = outp + (size_t)b * Cn * HWn;
  const int ibase = i0 + wv * 16 + lq * 4;
#pragma unroll
  for (int cs = 0; cs < 16; ++cs) {
    int c = cs * 16 + l15;
    float4 r4;
    r4.x = o_acc[cs][0] * i0v;
    r4.y = o_acc[cs][1] * i1v;
    r4.z = o_acc[cs][2] * i2v;
    r4.w = o_acc[cs][3] * i3v;
    *(float4*)(ob + (size_t)c * HWn + ibase) = r4;
  }
}

// ---------------- K4: output projection + bias + residual ----------------
__global__ __launch_bounds__(256)
void out_gemm_kernel(const float* __restrict__ tmp, const float* __restrict__ w,
                     const float* __restrict__ wb, const float* __restrict__ xres,
                     float* __restrict__ y) {
  const int b = blockIdx.z;
  const int m0 = blockIdx.y * 64, n0 = blockIdx.x * 64;
  const int tid = threadIdx.x, tx = tid & 15, ty = tid >> 4;
  __shared__ float As[16][68];
  __shared__ float Bs[16][68];
  const float* tb = tmp + (size_t)b * Cn * HWn;
  float acc[4][4] = {};
  const int am = tid >> 2, ak = (tid & 3) * 4;
  const int bk = tid >> 4, bn = (tid & 15) * 4;
  for (int k0 = 0; k0 < Cn; k0 += 16) {
    {
      float4 a = *(const float4*)(w + (size_t)(m0 + am) * Cn + (k0 + ak));
      As[ak + 0][am] = a.x; As[ak + 1][am] = a.y; As[ak + 2][am] = a.z; As[ak + 3][am] = a.w;
      int c = k0 + bk;
      float4 vv = *(const float4*)(tb + (size_t)c * HWn + (n0 + bn));
      Bs[bk][bn + 0] = vv.x; Bs[bk][bn + 1] = vv.y; Bs[bk][bn + 2] = vv.z; Bs[bk][bn + 3] = vv.w;
    }
    __syncthreads();
#pragma unroll
    for (int kk = 0; kk < 16; ++kk) {
      float4 av = *(const float4*)&As[kk][ty * 4];
      float4 bv = *(const float4*)&Bs[kk][tx * 4];
      float aa[4] = {av.x, av.y, av.z, av.w};
      float bb[4] = {bv.x, bv.y, bv.z, bv.w};
#pragma unroll
      for (int i2 = 0; i2 < 4; ++i2)
#pragma unroll
        for (int j2 = 0; j2 < 4; ++j2)
          acc[i2][j2] = fmaf(aa[i2], bb[j2], acc[i2][j2]);
    }
    __syncthreads();
  }
  float* yb = y + (size_t)b * Cn * HWn;
  const float* xb = xres + (size_t)b * Cn * HWn;
#pragma unroll
  for (int i2 = 0; i2 < 4; ++i2) {
    int m = m0 + ty * 4 + i2;
    float bias = wb[m];
    float4 xr = *(const float4*)(xb + (size_t)m * HWn + n0 + tx * 4);
    float4 r;
    r.x = acc[i2][0] + bias + xr.x; r.y = acc[i2][1] + bias + xr.y;
    r.z = acc[i2][2] + bias + xr.z; r.w = acc[i2][3] + bias + xr.w;
    *(float4*)(yb + (size_t)m * HWn + n0 + tx * 4) = r;
  }
}

extern "C" void kernel_launch(void* const* d_in, const int* in_sizes, int n_in,
                              void* d_out, int out_size, void* d_ws, size_t ws_size,
                              hipStream_t stream) {
  (void)in_sizes; (void)n_in; (void)out_size; (void)ws_size;
  const float* x     = (const float*)d_in[0];
  const float* gn_w  = (const float*)d_in[1];
  const float* gn_b  = (const float*)d_in[2];
  const float* qkv_w = (const float*)d_in[3];
  const float* qkv_b = (const float*)d_in[4];
  const float* out_w = (const float*)d_in[5];
  const float* out_b = (const float*)d_in[6];
  float* out = (float*)d_out;

  char* ws = (char*)d_ws;
  float* s_aff = (float*)ws;                                   // B*C
  float* t_aff = s_aff + Bn * Cn;                              // B*C
  unsigned short* Qt = (unsigned short*)(ws + 16384);          // 16MB
  unsigned short* Kt = Qt + (size_t)Bn * HWn * Cn;             // 16MB
  unsigned short* Vb = Kt + (size_t)Bn * HWn * Cn;             // 16MB
  float* tmp = (float*)(Vb + (size_t)Bn * HWn * Cn);           // 32MB

  gn_stats_kernel<<<dim3(Bn * Gn), 1024, 0, stream>>>(x, gn_w, gn_b, s_aff, t_aff);
  qkv_gemm_kernel<<<dim3(64, 12, Bn), 256, 0, stream>>>(x, qkv_w, qkv_b, s_aff, t_aff, Qt, Kt, Vb);
  attn_kernel<<<dim3(512), 256, 0, stream>>>(Qt, Kt, Vb, tmp);
  out_gemm_kernel<<<dim3(64, 4, Bn), 256, 0, stream>>>(tmp, out_w, out_b, x, out);
}

// Round 8
// 482.127 us; speedup vs baseline: 1.9348x; 1.0423x over previous
//
#include <hip/hip_runtime.h>
#include <math.h>

// AttentionBlock: B=8, C=256, HW=4096. Round 8:
//   attn = R6 geometry (KV tile 32j, LDS 32KB -> 4 blocks/CU) but with
//   __launch_bounds__(256,2) — R6's (256,4) forced VGPR=64 + 1.16GB spills.
//   Keeps: XCD grid (b=bid&7), defer-rescale THR=8, chunk-linear LDS,
//   in-register softmax, reg double-buffer staging.
// ws: s,t (16KB) | Qt 16MB | Kt 16MB | V 16MB | tmp fp32 32MB

#define Bn 8
#define Cn 256
#define HWn 4096
#define Gn 8
#define CPGn 32
#define Mqkv 768
#define EPSf 1e-5f
#define QSCALEf 0.0625f   // 1/sqrt(256), exact in bf16
#define RTHR 8.0f

typedef short bf16x8 __attribute__((ext_vector_type(8)));
typedef float f32x4 __attribute__((ext_vector_type(4)));

__device__ __forceinline__ unsigned short f2bf(float f) {
  union { float f; unsigned u; } v; v.f = f;
  unsigned r = v.u + 0x7FFFu + ((v.u >> 16) & 1u);  // RNE
  return (unsigned short)(r >> 16);
}

__device__ __forceinline__ int cvt_pk_bf16(float lo, float hi) {
  int d;
  asm("v_cvt_pk_bf16_f32 %0, %1, %2" : "=v"(d) : "v"(lo), "v"(hi));
  return d;
}

// ---------------- K1: group-norm stats -> per-channel affine ----------------
__global__ __launch_bounds__(1024)
void gn_stats_kernel(const float* __restrict__ x, const float* __restrict__ gn_w,
                     const float* __restrict__ gn_b, float* __restrict__ s_out,
                     float* __restrict__ t_out) {
  const int b = blockIdx.x / Gn, g = blockIdx.x % Gn;
  const float4* base = (const float4*)(x + ((size_t)(b * Cn + g * CPGn)) * HWn);
  const int n4 = CPGn * HWn / 4;
  float sum = 0.f, sq = 0.f;
  for (int i = threadIdx.x; i < n4; i += 1024) {
    float4 v = base[i];
    sum += (v.x + v.y) + (v.z + v.w);
    sq  += (v.x * v.x + v.y * v.y) + (v.z * v.z + v.w * v.w);
  }
  __shared__ float ss[1024], s2[1024];
  ss[threadIdx.x] = sum; s2[threadIdx.x] = sq;
  __syncthreads();
  for (int off = 512; off > 0; off >>= 1) {
    if ((int)threadIdx.x < off) {
      ss[threadIdx.x] += ss[threadIdx.x + off];
      s2[threadIdx.x] += s2[threadIdx.x + off];
    }
    __syncthreads();
  }
  if (threadIdx.x < CPGn) {
    const float inv_n = 1.f / (float)(CPGn * HWn);
    float mean = ss[0] * inv_n;
    float var  = s2[0] * inv_n - mean * mean;
    float rstd = rsqrtf(var + EPSf);
    int c = g * CPGn + (int)threadIdx.x;
    float sc = gn_w[c] * rstd;
    s_out[b * Cn + c] = sc;
    t_out[b * Cn + c] = gn_b[c] - mean * sc;
  }
}

// ---------------- K2: QKV GEMM (fp32) -> bf16 Q^T/K^T/V ----------------
__global__ __launch_bounds__(256)
void qkv_gemm_kernel(const float* __restrict__ x, const float* __restrict__ w,
                     const float* __restrict__ wb, const float* __restrict__ s_aff,
                     const float* __restrict__ t_aff, unsigned short* __restrict__ Qt,
                     unsigned short* __restrict__ Kt, unsigned short* __restrict__ Vb) {
  const int b = blockIdx.z;
  const int m0 = blockIdx.y * 64, n0 = blockIdx.x * 64;
  const int tid = threadIdx.x, tx = tid & 15, ty = tid >> 4;
  __shared__ float As[16][68];
  __shared__ float Bs[16][68];
  const float* xb = x + (size_t)b * Cn * HWn;
  const float* sb = s_aff + b * Cn;
  const float* tb = t_aff + b * Cn;
  float acc[4][4] = {};
  const int am = tid >> 2, ak = (tid & 3) * 4;
  const int bk = tid >> 4, bn = (tid & 15) * 4;
  for (int k0 = 0; k0 < Cn; k0 += 16) {
    {
      float4 a = *(const float4*)(w + (size_t)(m0 + am) * Cn + (k0 + ak));
      As[ak + 0][am] = a.x; As[ak + 1][am] = a.y; As[ak + 2][am] = a.z; As[ak + 3][am] = a.w;
      int c = k0 + bk;
      float4 v = *(const float4*)(xb + (size_t)c * HWn + (n0 + bn));
      float sc = sb[c], sh = tb[c];
      Bs[bk][bn + 0] = v.x * sc + sh; Bs[bk][bn + 1] = v.y * sc + sh;
      Bs[bk][bn + 2] = v.z * sc + sh; Bs[bk][bn + 3] = v.w * sc + sh;
    }
    __syncthreads();
#pragma unroll
    for (int kk = 0; kk < 16; ++kk) {
      float4 av = *(const float4*)&As[kk][ty * 4];
      float4 bv = *(const float4*)&Bs[kk][tx * 4];
      float aa[4] = {av.x, av.y, av.z, av.w};
      float bb[4] = {bv.x, bv.y, bv.z, bv.w};
#pragma unroll
      for (int i2 = 0; i2 < 4; ++i2)
#pragma unroll
        for (int j2 = 0; j2 < 4; ++j2)
          acc[i2][j2] = fmaf(aa[i2], bb[j2], acc[i2][j2]);
    }
    __syncthreads();
  }
  float bias[4];
#pragma unroll
  for (int i2 = 0; i2 < 4; ++i2) bias[i2] = wb[m0 + ty * 4 + i2];

  if (m0 < 512) {  // Q or K -> transposed [n][c] bf16; Q prescaled by 1/16
    unsigned short* dst = (m0 < 256) ? Qt : Kt;
    const float scl = (m0 < 256) ? QSCALEf : 1.0f;
    const int cbase = (m0 & 255) + ty * 4;
#pragma unroll
    for (int j2 = 0; j2 < 4; ++j2) {
      int n = n0 + tx * 4 + j2;
      ushort4 pk;
      pk.x = f2bf((acc[0][j2] + bias[0]) * scl);
      pk.y = f2bf((acc[1][j2] + bias[1]) * scl);
      pk.z = f2bf((acc[2][j2] + bias[2]) * scl);
      pk.w = f2bf((acc[3][j2] + bias[3]) * scl);
      *(ushort4*)(dst + ((size_t)(b * HWn + n) * Cn + cbase)) = pk;
    }
  } else {  // V -> [c][n] bf16
#pragma unroll
    for (int i2 = 0; i2 < 4; ++i2) {
      int c = (m0 - 512) + ty * 4 + i2;
      ushort4 pk;
      pk.x = f2bf(acc[i2][0] + bias[i2]);
      pk.y = f2bf(acc[i2][1] + bias[i2]);
      pk.z = f2bf(acc[i2][2] + bias[i2]);
      pk.w = f2bf(acc[i2][3] + bias[i2]);
      *(ushort4*)(Vb + ((size_t)(b * Cn + c) * HWn + n0 + tx * 4)) = pk;
    }
  }
}

// ---------------- K3: flash attention, bf16 MFMA ----------------
// 1D grid of 512: b = bid&7 (XCD-resident KV), qtile i0 = (bid>>3)*64.
// 4 waves x 16 q-rows. KV tile = 32 j. LDS 32KB chunk-linear (16B chunks):
//   Ks chunk = kc*128 + s*64 + lane : K[j=s*16+(lane&15)][c=kc*32+(lane>>4)*8 ..+7]
//   Vs chunk = cs*64 + lane         : V[c=cs*16+(lane&15)][j=(lane>>4)*8 ..+7]
// All LDS ops = lane*16 + imm (conflict-free); perm folded into global addrs.
__global__ __launch_bounds__(256, 2)
void attn_kernel(const unsigned short* __restrict__ Qt,
                 const unsigned short* __restrict__ Kt,
                 const unsigned short* __restrict__ Vb,
                 float* __restrict__ outp) {
  const int bid = blockIdx.x;
  const int b = bid & 7, i0 = (bid >> 3) * 64;
  const int tid = threadIdx.x;
  const int wv = tid >> 6, l = tid & 63;
  const int l15 = l & 15, lq = l >> 4;

  __shared__ unsigned short Ks[8192];  // 16KB
  __shared__ unsigned short Vs[8192];  // 16KB
  char* KsB = (char*)Ks;
  char* VsB = (char*)Vs;

  const unsigned short* Qb = Qt + ((size_t)b * HWn + i0) * Cn;
  const unsigned short* Kb = Kt + (size_t)b * HWn * Cn;
  const unsigned short* Vg = Vb + (size_t)b * Cn * HWn;

  // hoisted Q fragments (prescaled): B-frag Q[i=l15][k=kc*32+lq*8+t]
  bf16x8 qf[8];
  {
    const unsigned short* qrow = Qb + (size_t)(wv * 16 + l15) * Cn + lq * 8;
#pragma unroll
    for (int kc = 0; kc < 8; ++kc) qf[kc] = *(const bf16x8*)(qrow + kc * 32);
  }

  // staging maps (thread tid owns chunks q*256+tid, q=0..3)
  const int jk = ((tid >> 6) & 1) * 16 + (tid & 15);          // K row j (0..31)
  const int ck = (tid >> 7) * 32 + ((tid >> 4) & 3) * 8;      // K col base; +q*64
  const int cv = (tid >> 6) * 16 + (tid & 15);                // V row c base; +q*64
  const int jv = ((tid >> 4) & 3) * 8;                        // V col j
  const unsigned short* gK = Kb + (size_t)jk * Cn + ck;
  const unsigned short* gV = Vg + (size_t)cv * HWn + jv;

  // P redistribution lanes (select post-shuffle by shi = lq>>1)
  const int laneA = l15 + ((lq & 1) << 5);
  const int laneB = laneA + 16;
  const int shi = lq >> 1;

  bf16x8 kst[4], vst[4];
#pragma unroll
  for (int q = 0; q < 4; ++q) kst[q] = *(const bf16x8*)(gK + q * 64);
#pragma unroll
  for (int q = 0; q < 4; ++q) vst[q] = *(const bf16x8*)(gV + (size_t)q * 64 * HWn);
  gK += 32 * Cn; gV += 32;

  f32x4 o_acc[16];
#pragma unroll
  for (int cs = 0; cs < 16; ++cs) o_acc[cs] = (f32x4)(0.f);
  float m_i = -INFINITY, l_i = 0.f;

#pragma unroll 1
  for (int t = 0; t < 128; ++t) {
    // ---- write staged tile to LDS ----
#pragma unroll
    for (int q = 0; q < 4; ++q) *(bf16x8*)(KsB + tid * 16 + q * 4096) = kst[q];
#pragma unroll
    for (int q = 0; q < 4; ++q) *(bf16x8*)(VsB + tid * 16 + q * 4096) = vst[q];
    __syncthreads();
    // ---- issue next-tile loads (overlap with compute) ----
    if (t < 127) {
#pragma unroll
      for (int q = 0; q < 4; ++q) kst[q] = *(const bf16x8*)(gK + q * 64);
#pragma unroll
      for (int q = 0; q < 4; ++q) vst[q] = *(const bf16x8*)(gV + (size_t)q * 64 * HWn);
      gK += 32 * Cn; gV += 32;
    }

    // ---- S^T = K Q^T: lane holds S[i=l15][j=16s+4lq+r], s=0..1 ----
    f32x4 s0 = (f32x4)(0.f), s1 = (f32x4)(0.f);
#pragma unroll
    for (int kc = 0; kc < 8; ++kc) {
      bf16x8 kf0 = *(const bf16x8*)(KsB + l * 16 + kc * 2048);
      bf16x8 kf1 = *(const bf16x8*)(KsB + l * 16 + kc * 2048 + 1024);
      s0 = __builtin_amdgcn_mfma_f32_16x16x32_bf16(kf0, qf[kc], s0, 0, 0, 0);
      s1 = __builtin_amdgcn_mfma_f32_16x16x32_bf16(kf1, qf[kc], s1, 0, 0, 0);
    }

    // ---- per-lane online softmax (defer-rescale, THR=8) ----
    float p[2][4];
#pragma unroll
    for (int r = 0; r < 4; ++r) { p[0][r] = s0[r]; p[1][r] = s1[r]; }
    float rm = fmaxf(fmaxf(fmaxf(p[0][0], p[0][1]), fmaxf(p[0][2], p[0][3])),
                     fmaxf(fmaxf(p[1][0], p[1][1]), fmaxf(p[1][2], p[1][3])));
    rm = fmaxf(rm, __shfl_xor(rm, 16));
    rm = fmaxf(rm, __shfl_xor(rm, 32));
    if (!__all(rm - m_i <= RTHR)) {
      float mn = fmaxf(m_i, rm);
      float alpha = __expf(m_i - mn);
      m_i = mn;
      l_i *= alpha;
      float a0 = __shfl(alpha, 4 * lq + 0);
      float a1 = __shfl(alpha, 4 * lq + 1);
      float a2 = __shfl(alpha, 4 * lq + 2);
      float a3 = __shfl(alpha, 4 * lq + 3);
#pragma unroll
      for (int cs = 0; cs < 16; ++cs) {
        o_acc[cs][0] *= a0; o_acc[cs][1] *= a1;
        o_acc[cs][2] *= a2; o_acc[cs][3] *= a3;
      }
    }
    float rs = 0.f;
#pragma unroll
    for (int s = 0; s < 2; ++s)
#pragma unroll
      for (int r = 0; r < 4; ++r) { float e = __expf(p[s][r] - m_i); p[s][r] = e; rs += e; }
    rs += __shfl_xor(rs, 16);
    rs += __shfl_xor(rs, 32);
    l_i += rs;

    // ---- pack P: d[s][u] = bf16 pair P[i][s*16+4lq+2u, +1] ----
    int d00 = cvt_pk_bf16(p[0][0], p[0][1]), d01 = cvt_pk_bf16(p[0][2], p[0][3]);
    int d10 = cvt_pk_bf16(p[1][0], p[1][1]), d11 = cvt_pk_bf16(p[1][2], p[1][3]);
    // ---- redistribute to PV A-frag pa = P[i=l15][j=lq*8+t] ----
    int A00 = __shfl(d00, laneA), A01 = __shfl(d01, laneA);
    int A10 = __shfl(d10, laneA), A11 = __shfl(d11, laneA);
    int B00 = __shfl(d00, laneB), B01 = __shfl(d01, laneB);
    int B10 = __shfl(d10, laneB), B11 = __shfl(d11, laneB);
    union { int w[4]; bf16x8 v; } pa;
    pa.w[0] = shi ? A10 : A00; pa.w[1] = shi ? A11 : A01;
    pa.w[2] = shi ? B10 : B00; pa.w[3] = shi ? B11 : B01;

    // ---- O += P V ----
#pragma unroll
    for (int cs = 0; cs < 16; ++cs) {
      bf16x8 vf = *(const bf16x8*)(VsB + l * 16 + cs * 1024);
      o_acc[cs] = __builtin_amdgcn_mfma_f32_16x16x32_bf16(pa.v, vf, o_acc[cs], 0, 0, 0);
    }
    __syncthreads();
  }

  // ---- epilogue: O /= l, write tmp fp32 [c][i] ----
  float il = 1.f / l_i;
  float i0v = __shfl(il, 4 * lq + 0);
  float i1v = __shfl(il, 4 * lq + 1);
  float i2v = __shfl(il, 4 * lq + 2);
  float i3v = __shfl(il, 4 * lq + 3);
  float* ob = outp + (size_t)b * Cn * HWn;
  const int ibase = i0 + wv * 16 + lq * 4;
#pragma unroll
  for (int cs = 0; cs < 16; ++cs) {
    int c = cs * 16 + l15;
    float4 r4;
    r4.x = o_acc[cs][0] * i0v;
    r4.y = o_acc[cs][1] * i1v;
    r4.z = o_acc[cs][2] * i2v;
    r4.w = o_acc[cs][3] * i3v;
    *(float4*)(ob + (size_t)c * HWn + ibase) = r4;
  }
}

// ---------------- K4: output projection + bias + residual ----------------
__global__ __launch_bounds__(256)
void out_gemm_kernel(const float* __restrict__ tmp, const float* __restrict__ w,
                     const float* __restrict__ wb, const float* __restrict__ xres,
                     float* __restrict__ y) {
  const int b = blockIdx.z;
  const int m0 = blockIdx.y * 64, n0 = blockIdx.x * 64;
  const int tid = threadIdx.x, tx = tid & 15, ty = tid >> 4;
  __shared__ float As[16][68];
  __shared__ float Bs[16][68];
  const float* tb = tmp + (size_t)b * Cn * HWn;
  float acc[4][4] = {};
  const int am = tid >> 2, ak = (tid & 3) * 4;
  const int bk = tid >> 4, bn = (tid & 15) * 4;
  for (int k0 = 0; k0 < Cn; k0 += 16) {
    {
      float4 a = *(const float4*)(w + (size_t)(m0 + am) * Cn + (k0 + ak));
      As[ak + 0][am] = a.x; As[ak + 1][am] = a.y; As[ak + 2][am] = a.z; As[ak + 3][am] = a.w;
      int c = k0 + bk;
      float4 vv = *(const float4*)(tb + (size_t)c * HWn + (n0 + bn));
      Bs[bk][bn + 0] = vv.x; Bs[bk][bn + 1] = vv.y; Bs[bk][bn + 2] = vv.z; Bs[bk][bn + 3] = vv.w;
    }
    __syncthreads();
#pragma unroll
    for (int kk = 0; kk < 16; ++kk) {
      float4 av = *(const float4*)&As[kk][ty * 4];
      float4 bv = *(const float4*)&Bs[kk][tx * 4];
      float aa[4] = {av.x, av.y, av.z, av.w};
      float bb[4] = {bv.x, bv.y, bv.z, bv.w};
#pragma unroll
      for (int i2 = 0; i2 < 4; ++i2)
#pragma unroll
        for (int j2 = 0; j2 < 4; ++j2)
          acc[i2][j2] = fmaf(aa[i2], bb[j2], acc[i2][j2]);
    }
    __syncthreads();
  }
  float* yb = y + (size_t)b * Cn * HWn;
  const float* xb = xres + (size_t)b * Cn * HWn;
#pragma unroll
  for (int i2 = 0; i2 < 4; ++i2) {
    int m = m0 + ty * 4 + i2;
    float bias = wb[m];
    float4 xr = *(const float4*)(xb + (size_t)m * HWn + n0 + tx * 4);
    float4 r;
    r.x = acc[i2][0] + bias + xr.x; r.y = acc[i2][1] + bias + xr.y;
    r.z = acc[i2][2] + bias + xr.z; r.w = acc[i2][3] + bias + xr.w;
    *(float4*)(yb + (size_t)m * HWn + n0 + tx * 4) = r;
  }
}

extern "C" void kernel_launch(void* const* d_in, const int* in_sizes, int n_in,
                              void* d_out, int out_size, void* d_ws, size_t ws_size,
                              hipStream_t stream) {
  (void)in_sizes; (void)n_in; (void)out_size; (void)ws_size;
  const float* x     = (const float*)d_in[0];
  const float* gn_w  = (const float*)d_in[1];
  const float* gn_b  = (const float*)d_in[2];
  const float* qkv_w = (const float*)d_in[3];
  const float* qkv_b = (const float*)d_in[4];
  const float* out_w = (const float*)d_in[5];
  const float* out_b = (const float*)d_in[6];
  float* out = (float*)d_out;

  char* ws = (char*)d_ws;
  float* s_aff = (float*)ws;                                   // B*C
  float* t_aff = s_aff + Bn * Cn;                              // B*C
  unsigned short* Qt = (unsigned short*)(ws + 16384);          // 16MB
  unsigned short* Kt = Qt + (size_t)Bn * HWn * Cn;             // 16MB
  unsigned short* Vb = Kt + (size_t)Bn * HWn * Cn;             // 16MB
  float* tmp = (float*)(Vb + (size_t)Bn * HWn * Cn);           // 32MB

  gn_stats_kernel<<<dim3(Bn * Gn), 1024, 0, stream>>>(x, gn_w, gn_b, s_aff, t_aff);
  qkv_gemm_kernel<<<dim3(64, 12, Bn), 256, 0, stream>>>(x, qkv_w, qkv_b, s_aff, t_aff, Qt, Kt, Vb);
  attn_kernel<<<dim3(512), 256, 0, stream>>>(Qt, Kt, Vb, tmp);
  out_gemm_kernel<<<dim3(64, 4, Bn), 256, 0, stream>>>(tmp, out_w, out_b, x, out);
}

// Round 9
// 397.220 us; speedup vs baseline: 2.3483x; 1.2138x over previous
//
#include <hip/hip_runtime.h>
#include <math.h>

// AttentionBlock: B=8, C=256, HW=4096. Round 9: MFMA everywhere.
//   K1  gn_stats: per-(b,group) stats -> per-(b,c) affine s,t
//   K1b affine_transpose: nxT[b][n][c] bf16 (GN applied)  -- makes k-dim contiguous
//   K2  qkv_gemm: LDS-free bf16 MFMA; A=w frags (hoisted), B=nxT rows from global.
//       Q/K: mfma(w,x) -> ushort4 stores into [n][c]; V: mfma(x,w) -> ushort4 into [c][n]
//   K3  attn: unchanged structure (R8), epilogue now writes tmpT[n][c] bf16
//   K4  out_gemm: LDS-free bf16 MFMA, swapped operands -> float4 y-stores + residual
// ws: s,t 16KB | Qt 16MB | Kt 16MB | Vb 16MB | nxT 16MB | tmpT 16MB

#define Bn 8
#define Cn 256
#define HWn 4096
#define Gn 8
#define CPGn 32
#define Mqkv 768
#define EPSf 1e-5f
#define QSCALEf 0.0625f   // 1/sqrt(256), exact in bf16
#define RTHR 8.0f

typedef short bf16x8 __attribute__((ext_vector_type(8)));
typedef float f32x4 __attribute__((ext_vector_type(4)));

__device__ __forceinline__ unsigned short f2bf(float f) {
  union { float f; unsigned u; } v; v.f = f;
  unsigned r = v.u + 0x7FFFu + ((v.u >> 16) & 1u);  // RNE
  return (unsigned short)(r >> 16);
}

__device__ __forceinline__ int cvt_pk_bf16(float lo, float hi) {
  int d;
  asm("v_cvt_pk_bf16_f32 %0, %1, %2" : "=v"(d) : "v"(lo), "v"(hi));
  return d;
}

// ---------------- K1: group-norm stats -> per-channel affine ----------------
__global__ __launch_bounds__(1024)
void gn_stats_kernel(const float* __restrict__ x, const float* __restrict__ gn_w,
                     const float* __restrict__ gn_b, float* __restrict__ s_out,
                     float* __restrict__ t_out) {
  const int b = blockIdx.x / Gn, g = blockIdx.x % Gn;
  const float4* base = (const float4*)(x + ((size_t)(b * Cn + g * CPGn)) * HWn);
  const int n4 = CPGn * HWn / 4;
  float sum = 0.f, sq = 0.f;
  for (int i = threadIdx.x; i < n4; i += 1024) {
    float4 v = base[i];
    sum += (v.x + v.y) + (v.z + v.w);
    sq  += (v.x * v.x + v.y * v.y) + (v.z * v.z + v.w * v.w);
  }
  __shared__ float ss[1024], s2[1024];
  ss[threadIdx.x] = sum; s2[threadIdx.x] = sq;
  __syncthreads();
  for (int off = 512; off > 0; off >>= 1) {
    if ((int)threadIdx.x < off) {
      ss[threadIdx.x] += ss[threadIdx.x + off];
      s2[threadIdx.x] += s2[threadIdx.x + off];
    }
    __syncthreads();
  }
  if (threadIdx.x < CPGn) {
    const float inv_n = 1.f / (float)(CPGn * HWn);
    float mean = ss[0] * inv_n;
    float var  = s2[0] * inv_n - mean * mean;
    float rstd = rsqrtf(var + EPSf);
    int c = g * CPGn + (int)threadIdx.x;
    float sc = gn_w[c] * rstd;
    s_out[b * Cn + c] = sc;
    t_out[b * Cn + c] = gn_b[c] - mean * sc;
  }
}

// ---------------- K1b: affine + transpose -> nxT[b][n][c] bf16 ----------------
__global__ __launch_bounds__(256)
void affine_transpose_kernel(const float* __restrict__ x, const float* __restrict__ s_aff,
                             const float* __restrict__ t_aff, unsigned short* __restrict__ nxT) {
  const int bid = blockIdx.x;
  const int b = bid & 7, r = bid >> 3;
  const int c0 = (r & 3) * 64, n0 = (r >> 2) * 64;
  const int tid = threadIdx.x;
  __shared__ unsigned int ld32[64][33];   // [c][n/2] packed bf16 pairs, padded
  const float* xb = x + ((size_t)(b * Cn + c0)) * HWn + n0;
  const int cl0 = tid >> 4, nn = (tid & 15) * 4;
#pragma unroll
  for (int it = 0; it < 4; ++it) {
    int cl = cl0 + 16 * it;
    int c = c0 + cl;
    float sc = s_aff[b * Cn + c], sh = t_aff[b * Cn + c];
    float4 v = *(const float4*)(xb + (size_t)cl * HWn + nn);
    ld32[cl][(nn >> 1) + 0] = (unsigned)cvt_pk_bf16(v.x * sc + sh, v.y * sc + sh);
    ld32[cl][(nn >> 1) + 1] = (unsigned)cvt_pk_bf16(v.z * sc + sh, v.w * sc + sh);
  }
  __syncthreads();
#pragma unroll
  for (int it = 0; it < 2; ++it) {
    int chunk = tid + 256 * it;
    int n = chunk >> 3, cg = chunk & 7;
    union { unsigned short u[8]; bf16x8 v; } o;
#pragma unroll
    for (int k = 0; k < 8; ++k) {
      unsigned w32 = ld32[cg * 8 + k][n >> 1];
      o.u[k] = (unsigned short)((n & 1) ? (w32 >> 16) : (w32 & 0xffffu));
    }
    *(bf16x8*)(nxT + ((size_t)(b * HWn + n0 + n)) * Cn + c0 + cg * 8) = o.v;
  }
}

// ---------------- K2: QKV GEMM, LDS-free bf16 MFMA ----------------
// grid 3072: b=bid&7; r=bid>>3: n0=(r&63)*64, m0=(r>>6)*128 (o-tile of 128, 4 waves x 32 o).
// A-frag wf: w rows (fp32->bf16, hoisted). B-frag xf: nxT[n][c] direct global reads.
// Q/K (m0<512): acc=mfma(wf,xf): C[o][n], lane: n=l15 fixed, o=lq*4+u -> ushort4 along c.
// V  (m0>=512): acc=mfma(xf,wf): C[n][o], lane: o=l15 fixed, n=lq*4+u -> ushort4 along n.
__global__ __launch_bounds__(256, 2)
void qkv_gemm_kernel(const unsigned short* __restrict__ nxT, const float* __restrict__ w,
                     const float* __restrict__ wb, unsigned short* __restrict__ Qt,
                     unsigned short* __restrict__ Kt, unsigned short* __restrict__ Vb) {
  const int bid = blockIdx.x;
  const int b = bid & 7, r = bid >> 3;
  const int n0 = (r & 63) * 64, m0 = (r >> 6) * 128;
  const int tid = threadIdx.x;
  const int wv = tid >> 6, l = tid & 63;
  const int l15 = l & 15, lq = l >> 4;
  const int ob = m0 + wv * 32;

  bf16x8 wf[2][8];
#pragma unroll
  for (int g = 0; g < 2; ++g) {
    const float* wr = w + (size_t)(ob + g * 16 + l15) * Cn + lq * 8;
#pragma unroll
    for (int kc = 0; kc < 8; ++kc) {
      float4 a = *(const float4*)(wr + kc * 32);
      float4 c4 = *(const float4*)(wr + kc * 32 + 4);
      union { int w4[4]; bf16x8 v; } u;
      u.w4[0] = cvt_pk_bf16(a.x, a.y);  u.w4[1] = cvt_pk_bf16(a.z, a.w);
      u.w4[2] = cvt_pk_bf16(c4.x, c4.y); u.w4[3] = cvt_pk_bf16(c4.z, c4.w);
      wf[g][kc] = u.v;
    }
  }

  const unsigned short* nb = nxT + (size_t)b * HWn * Cn + lq * 8;
  f32x4 acc[2][4];
#pragma unroll
  for (int g = 0; g < 2; ++g)
#pragma unroll
    for (int s = 0; s < 4; ++s) acc[g][s] = (f32x4)(0.f);

  const bool isV = (m0 >= 512);
#pragma unroll
  for (int s = 0; s < 4; ++s) {
    const unsigned short* np = nb + (size_t)(n0 + s * 16 + l15) * Cn;
#pragma unroll
    for (int kc = 0; kc < 8; ++kc) {
      bf16x8 xf = *(const bf16x8*)(np + kc * 32);
      if (!isV) {
        acc[0][s] = __builtin_amdgcn_mfma_f32_16x16x32_bf16(wf[0][kc], xf, acc[0][s], 0, 0, 0);
        acc[1][s] = __builtin_amdgcn_mfma_f32_16x16x32_bf16(wf[1][kc], xf, acc[1][s], 0, 0, 0);
      } else {
        acc[0][s] = __builtin_amdgcn_mfma_f32_16x16x32_bf16(xf, wf[0][kc], acc[0][s], 0, 0, 0);
        acc[1][s] = __builtin_amdgcn_mfma_f32_16x16x32_bf16(xf, wf[1][kc], acc[1][s], 0, 0, 0);
      }
    }
  }

  if (!isV) {  // Q or K -> [n][c] ushort4 stores
    unsigned short* dst = (m0 < 256) ? Qt : Kt;
    const float scl = (m0 < 256) ? QSCALEf : 1.0f;
#pragma unroll
    for (int g = 0; g < 2; ++g) {
      int cb = ((ob + g * 16) & 255) + lq * 4;
      float b0 = wb[ob + g * 16 + lq * 4 + 0];
      float b1 = wb[ob + g * 16 + lq * 4 + 1];
      float b2 = wb[ob + g * 16 + lq * 4 + 2];
      float b3 = wb[ob + g * 16 + lq * 4 + 3];
#pragma unroll
      for (int s = 0; s < 4; ++s) {
        int n = n0 + s * 16 + l15;
        ushort4 pk;
        pk.x = f2bf((acc[g][s][0] + b0) * scl);
        pk.y = f2bf((acc[g][s][1] + b1) * scl);
        pk.z = f2bf((acc[g][s][2] + b2) * scl);
        pk.w = f2bf((acc[g][s][3] + b3) * scl);
        *(ushort4*)(dst + ((size_t)(b * HWn + n)) * Cn + cb) = pk;
      }
    }
  } else {     // V -> [c][n] ushort4 stores (swapped: lane fixed c=o-512, 4 contig n)
#pragma unroll
    for (int g = 0; g < 2; ++g) {
      int o = ob + g * 16 + l15;
      int c = o - 512;
      float bias = wb[o];
#pragma unroll
      for (int s = 0; s < 4; ++s) {
        int n = n0 + s * 16 + lq * 4;
        ushort4 pk;
        pk.x = f2bf(acc[g][s][0] + bias);
        pk.y = f2bf(acc[g][s][1] + bias);
        pk.z = f2bf(acc[g][s][2] + bias);
        pk.w = f2bf(acc[g][s][3] + bias);
        *(ushort4*)(Vb + ((size_t)(b * Cn + c)) * HWn + n) = pk;
      }
    }
  }
}

// ---------------- K3: flash attention (R8 structure; epilogue -> tmpT bf16) ----------------
__global__ __launch_bounds__(256, 2)
void attn_kernel(const unsigned short* __restrict__ Qt,
                 const unsigned short* __restrict__ Kt,
                 const unsigned short* __restrict__ Vb,
                 unsigned short* __restrict__ outp) {
  const int bid = blockIdx.x;
  const int b = bid & 7, i0 = (bid >> 3) * 64;
  const int tid = threadIdx.x;
  const int wv = tid >> 6, l = tid & 63;
  const int l15 = l & 15, lq = l >> 4;

  __shared__ unsigned short Ks[8192];  // 16KB
  __shared__ unsigned short Vs[8192];  // 16KB
  char* KsB = (char*)Ks;
  char* VsB = (char*)Vs;

  const unsigned short* Qb = Qt + ((size_t)b * HWn + i0) * Cn;
  const unsigned short* Kb = Kt + (size_t)b * HWn * Cn;
  const unsigned short* Vg = Vb + (size_t)b * Cn * HWn;

  bf16x8 qf[8];
  {
    const unsigned short* qrow = Qb + (size_t)(wv * 16 + l15) * Cn + lq * 8;
#pragma unroll
    for (int kc = 0; kc < 8; ++kc) qf[kc] = *(const bf16x8*)(qrow + kc * 32);
  }

  const int jk = ((tid >> 6) & 1) * 16 + (tid & 15);
  const int ck = (tid >> 7) * 32 + ((tid >> 4) & 3) * 8;
  const int cv = (tid >> 6) * 16 + (tid & 15);
  const int jv = ((tid >> 4) & 3) * 8;
  const unsigned short* gK = Kb + (size_t)jk * Cn + ck;
  const unsigned short* gV = Vg + (size_t)cv * HWn + jv;

  const int laneA = l15 + ((lq & 1) << 5);
  const int laneB = laneA + 16;
  const int shi = lq >> 1;

  bf16x8 kst[4], vst[4];
#pragma unroll
  for (int q = 0; q < 4; ++q) kst[q] = *(const bf16x8*)(gK + q * 64);
#pragma unroll
  for (int q = 0; q < 4; ++q) vst[q] = *(const bf16x8*)(gV + (size_t)q * 64 * HWn);
  gK += 32 * Cn; gV += 32;

  f32x4 o_acc[16];
#pragma unroll
  for (int cs = 0; cs < 16; ++cs) o_acc[cs] = (f32x4)(0.f);
  float m_i = -INFINITY, l_i = 0.f;

#pragma unroll 1
  for (int t = 0; t < 128; ++t) {
#pragma unroll
    for (int q = 0; q < 4; ++q) *(bf16x8*)(KsB + tid * 16 + q * 4096) = kst[q];
#pragma unroll
    for (int q = 0; q < 4; ++q) *(bf16x8*)(VsB + tid * 16 + q * 4096) = vst[q];
    __syncthreads();
    if (t < 127) {
#pragma unroll
      for (int q = 0; q < 4; ++q) kst[q] = *(const bf16x8*)(gK + q * 64);
#pragma unroll
      for (int q = 0; q < 4; ++q) vst[q] = *(const bf16x8*)(gV + (size_t)q * 64 * HWn);
      gK += 32 * Cn; gV += 32;
    }

    f32x4 s0 = (f32x4)(0.f), s1 = (f32x4)(0.f);
#pragma unroll
    for (int kc = 0; kc < 8; ++kc) {
      bf16x8 kf0 = *(const bf16x8*)(KsB + l * 16 + kc * 2048);
      bf16x8 kf1 = *(const bf16x8*)(KsB + l * 16 + kc * 2048 + 1024);
      s0 = __builtin_amdgcn_mfma_f32_16x16x32_bf16(kf0, qf[kc], s0, 0, 0, 0);
      s1 = __builtin_amdgcn_mfma_f32_16x16x32_bf16(kf1, qf[kc], s1, 0, 0, 0);
    }

    float p[2][4];
#pragma unroll
    for (int u = 0; u < 4; ++u) { p[0][u] = s0[u]; p[1][u] = s1[u]; }
    float rm = fmaxf(fmaxf(fmaxf(p[0][0], p[0][1]), fmaxf(p[0][2], p[0][3])),
                     fmaxf(fmaxf(p[1][0], p[1][1]), fmaxf(p[1][2], p[1][3])));
    rm = fmaxf(rm, __shfl_xor(rm, 16));
    rm = fmaxf(rm, __shfl_xor(rm, 32));
    if (!__all(rm - m_i <= RTHR)) {
      float mn = fmaxf(m_i, rm);
      float alpha = __expf(m_i - mn);
      m_i = mn;
      l_i *= alpha;
      float a0 = __shfl(alpha, 4 * lq + 0);
      float a1 = __shfl(alpha, 4 * lq + 1);
      float a2 = __shfl(alpha, 4 * lq + 2);
      float a3 = __shfl(alpha, 4 * lq + 3);
#pragma unroll
      for (int cs = 0; cs < 16; ++cs) {
        o_acc[cs][0] *= a0; o_acc[cs][1] *= a1;
        o_acc[cs][2] *= a2; o_acc[cs][3] *= a3;
      }
    }
    float rs = 0.f;
#pragma unroll
    for (int s = 0; s < 2; ++s)
#pragma unroll
      for (int u = 0; u < 4; ++u) { float e = __expf(p[s][u] - m_i); p[s][u] = e; rs += e; }
    rs += __shfl_xor(rs, 16);
    rs += __shfl_xor(rs, 32);
    l_i += rs;

    int d00 = cvt_pk_bf16(p[0][0], p[0][1]), d01 = cvt_pk_bf16(p[0][2], p[0][3]);
    int d10 = cvt_pk_bf16(p[1][0], p[1][1]), d11 = cvt_pk_bf16(p[1][2], p[1][3]);
    int A00 = __shfl(d00, laneA), A01 = __shfl(d01, laneA);
    int A10 = __shfl(d10, laneA), A11 = __shfl(d11, laneA);
    int B00 = __shfl(d00, laneB), B01 = __shfl(d01, laneB);
    int B10 = __shfl(d10, laneB), B11 = __shfl(d11, laneB);
    union { int w[4]; bf16x8 v; } pa;
    pa.w[0] = shi ? A10 : A00; pa.w[1] = shi ? A11 : A01;
    pa.w[2] = shi ? B10 : B00; pa.w[3] = shi ? B11 : B01;

#pragma unroll
    for (int cs = 0; cs < 16; ++cs) {
      bf16x8 vf = *(const bf16x8*)(VsB + l * 16 + cs * 1024);
      o_acc[cs] = __builtin_amdgcn_mfma_f32_16x16x32_bf16(pa.v, vf, o_acc[cs], 0, 0, 0);
    }
    __syncthreads();
  }

  // ---- epilogue: O /= l, write tmpT bf16 [n][c] ----
  float il = 1.f / l_i;
  float i0v = __shfl(il, 4 * lq + 0);
  float i1v = __shfl(il, 4 * lq + 1);
  float i2v = __shfl(il, 4 * lq + 2);
  float i3v = __shfl(il, 4 * lq + 3);
  unsigned short* ob = outp + (size_t)b * HWn * Cn;
  const int ibase = i0 + wv * 16 + lq * 4;
#pragma unroll
  for (int cs = 0; cs < 16; ++cs) {
    int c = cs * 16 + l15;
    ob[(size_t)(ibase + 0) * Cn + c] = f2bf(o_acc[cs][0] * i0v);
    ob[(size_t)(ibase + 1) * Cn + c] = f2bf(o_acc[cs][1] * i1v);
    ob[(size_t)(ibase + 2) * Cn + c] = f2bf(o_acc[cs][2] * i2v);
    ob[(size_t)(ibase + 3) * Cn + c] = f2bf(o_acc[cs][3] * i3v);
  }
}

// ---------------- K4: out projection, LDS-free bf16 MFMA (swapped) + residual ----------------
// grid 1024: b=bid&7; r=bid>>3: n0=(r&63)*64, m0=(r>>6)*128.
// acc = mfma(tf, wf): C[n][o]: lane o=l15 fixed, n=lq*4+u -> float4 stores + residual.
__global__ __launch_bounds__(256, 2)
void out_gemm_kernel(const unsigned short* __restrict__ tmpT, const float* __restrict__ w,
                     const float* __restrict__ wb, const float* __restrict__ xres,
                     float* __restrict__ y) {
  const int bid = blockIdx.x;
  const int b = bid & 7, r = bid >> 3;
  const int n0 = (r & 63) * 64, m0 = (r >> 6) * 128;
  const int tid = threadIdx.x;
  const int wv = tid >> 6, l = tid & 63;
  const int l15 = l & 15, lq = l >> 4;
  const int ob = m0 + wv * 32;

  bf16x8 wf[2][8];
#pragma unroll
  for (int g = 0; g < 2; ++g) {
    const float* wr = w + (size_t)(ob + g * 16 + l15) * Cn + lq * 8;
#pragma unroll
    for (int kc = 0; kc < 8; ++kc) {
      float4 a = *(const float4*)(wr + kc * 32);
      float4 c4 = *(const float4*)(wr + kc * 32 + 4);
      union { int w4[4]; bf16x8 v; } u;
      u.w4[0] = cvt_pk_bf16(a.x, a.y);  u.w4[1] = cvt_pk_bf16(a.z, a.w);
      u.w4[2] = cvt_pk_bf16(c4.x, c4.y); u.w4[3] = cvt_pk_bf16(c4.z, c4.w);
      wf[g][kc] = u.v;
    }
  }

  const unsigned short* tb = tmpT + (size_t)b * HWn * Cn + lq * 8;
  f32x4 acc[2][4];
#pragma unroll
  for (int g = 0; g < 2; ++g)
#pragma unroll
    for (int s = 0; s < 4; ++s) acc[g][s] = (f32x4)(0.f);

#pragma unroll
  for (int s = 0; s < 4; ++s) {
    const unsigned short* tp = tb + (size_t)(n0 + s * 16 + l15) * Cn;
#pragma unroll
    for (int kc = 0; kc < 8; ++kc) {
      bf16x8 tf = *(const bf16x8*)(tp + kc * 32);
      acc[0][s] = __builtin_amdgcn_mfma_f32_16x16x32_bf16(tf, wf[0][kc], acc[0][s], 0, 0, 0);
      acc[1][s] = __builtin_amdgcn_mfma_f32_16x16x32_bf16(tf, wf[1][kc], acc[1][s], 0, 0, 0);
    }
  }

#pragma unroll
  for (int g = 0; g < 2; ++g) {
    int o = ob + g * 16 + l15;
    float bias = wb[o];
#pragma unroll
    for (int s = 0; s < 4; ++s) {
      int n = n0 + s * 16 + lq * 4;
      size_t idx = ((size_t)(b * Cn + o)) * HWn + n;
      float4 xr = *(const float4*)(xres + idx);
      float4 out;
      out.x = acc[g][s][0] + bias + xr.x;
      out.y = acc[g][s][1] + bias + xr.y;
      out.z = acc[g][s][2] + bias + xr.z;
      out.w = acc[g][s][3] + bias + xr.w;
      *(float4*)(y + idx) = out;
    }
  }
}

extern "C" void kernel_launch(void* const* d_in, const int* in_sizes, int n_in,
                              void* d_out, int out_size, void* d_ws, size_t ws_size,
                              hipStream_t stream) {
  (void)in_sizes; (void)n_in; (void)out_size; (void)ws_size;
  const float* x     = (const float*)d_in[0];
  const float* gn_w  = (const float*)d_in[1];
  const float* gn_b  = (const float*)d_in[2];
  const float* qkv_w = (const float*)d_in[3];
  const float* qkv_b = (const float*)d_in[4];
  const float* out_w = (const float*)d_in[5];
  const float* out_b = (const float*)d_in[6];
  float* out = (float*)d_out;

  char* ws = (char*)d_ws;
  float* s_aff = (float*)ws;                                   // B*C
  float* t_aff = s_aff + Bn * Cn;                              // B*C
  unsigned short* Qt  = (unsigned short*)(ws + 16384);         // 16MB
  unsigned short* Kt  = Qt  + (size_t)Bn * HWn * Cn;           // 16MB
  unsigned short* Vb  = Kt  + (size_t)Bn * HWn * Cn;           // 16MB
  unsigned short* nxT = Vb  + (size_t)Bn * HWn * Cn;           // 16MB
  unsigned short* tmpT = nxT + (size_t)Bn * HWn * Cn;          // 16MB

  gn_stats_kernel<<<dim3(Bn * Gn), 1024, 0, stream>>>(x, gn_w, gn_b, s_aff, t_aff);
  affine_transpose_kernel<<<dim3(2048), 256, 0, stream>>>(x, s_aff, t_aff, nxT);
  qkv_gemm_kernel<<<dim3(3072), 256, 0, stream>>>(nxT, qkv_w, qkv_b, Qt, Kt, Vb);
  attn_kernel<<<dim3(512), 256, 0, stream>>>(Qt, Kt, Vb, tmpT);
  out_gemm_kernel<<<dim3(1024), 256, 0, stream>>>(tmpT, out_w, out_b, x, out);
}